// Round 6
// baseline (49.272 us; speedup 1.0000x reference)
//
#include <hip/hip_runtime.h>
#include <hip/hip_bf16.h>

#define NNODES 4096
#define NF 64
#define NH 8
#define ND 8
#define HD 64   // NH*ND

typedef unsigned long long u64;

// Load element i from a buffer that is either f32 or bf16 (uniform flag).
__device__ __forceinline__ float ldv(const void* p, int i, bool f32) {
    return f32 ? ((const float*)p)[i]
               : __bfloat162float(((const __hip_bfloat16*)p)[i]);
}

// A[0][0] == 1.0 always (self loop): first u32 == 0x3F800000 iff A is f32.
__device__ __forceinline__ bool a_is_f32(const void* A) {
    return *(const unsigned int*)A == 0x3F800000u;
}

// ---------------------------------------------------------------------------
// Kernel 1: feats = X @ W (f32), plus a_self/a_neigh logits per node.
// Block = 256 threads handles 4 rows of X. W staged in LDS as f32.
// (proven in round 4)
// ---------------------------------------------------------------------------
__global__ __launch_bounds__(256) void gat_feats(
    const void* __restrict__ X,
    const void* __restrict__ W,
    const void* __restrict__ att_self,
    const void* __restrict__ att_neigh,
    const void* __restrict__ A,
    float* __restrict__ feats,
    float* __restrict__ a_self,
    float* __restrict__ a_neigh)
{
    const bool f32 = a_is_f32(A);
    __shared__ float Wl[NF][HD];   // 16 KB
    __shared__ float Xl[4][NF];

    const int t = threadIdx.x;

    #pragma unroll
    for (int k = 0; k < 16; ++k) {
        int idx = t + k * 256;
        Wl[idx >> 6][idx & 63] = ldv(W, idx, f32);
    }

    const int n0 = blockIdx.x * 4;
    const int r = t >> 6;       // row within block (== wave id)
    const int c = t & 63;       // output column = h*8+d (== lane)
    Xl[r][c] = ldv(X, (n0 + r) * NF + c, f32);
    __syncthreads();

    float acc = 0.f;
    #pragma unroll
    for (int k = 0; k < NF; ++k)
        acc = fmaf(Xl[r][k], Wl[k][c], acc);

    const int n = n0 + r;
    feats[n * HD + c] = acc;

    const int d = c & 7;
    const int h = c >> 3;
    float vs = acc * ldv(att_self, c, f32);
    float vn = acc * ldv(att_neigh, c, f32);
    #pragma unroll
    for (int off = 1; off < 8; off <<= 1) {
        vs += __shfl_xor(vs, off, 64);
        vn += __shfl_xor(vn, off, 64);
    }
    if (d == 0) {
        a_self[n * NH + h]  = vs;
        a_neigh[n * NH + h] = vn;
    }
}

// ---------------------------------------------------------------------------
// Kernel 2: one ROW PER WAVE, no LDS, no __syncthreads.
// Lane l holds a 64-bit mask of A[i, l*64 .. l*64+63]; edges are streamed
// wave-uniformly (ballot + shfl + ffs, ascending j = deterministic order).
// lane = c = h*8+d accumulates acc(c) and den(h) in registers only.
// ---------------------------------------------------------------------------
__global__ __launch_bounds__(256) void gat_aggr(
    const void* __restrict__ A,
    const float* __restrict__ feats,
    const float* __restrict__ a_self_g,
    const float* __restrict__ a_neigh,
    const void* __restrict__ bias,
    float* __restrict__ out)
{
    const bool f32 = a_is_f32(A);
    const int lane = threadIdx.x & 63;
    const int i = (blockIdx.x << 2) + (threadIdx.x >> 6);   // one row per wave

    // ---- build this lane's 64-bit adjacency mask (64 consecutive j) ----
    u64 bits = 0;
    if (f32) {
        const uint4* ap = (const uint4*)((const float*)A + (size_t)i * NNODES + lane * 64);
        #pragma unroll
        for (int half = 0; half < 2; ++half) {
            unsigned int mw = 0;
            #pragma unroll
            for (int q = 0; q < 8; ++q) {
                uint4 p = ap[half * 8 + q];
                if (p.x) mw |= 1u << (4 * q + 0);
                if (p.y) mw |= 1u << (4 * q + 1);
                if (p.z) mw |= 1u << (4 * q + 2);
                if (p.w) mw |= 1u << (4 * q + 3);
            }
            bits |= (u64)mw << (32 * half);
        }
    } else {
        const uint4* ap = (const uint4*)((const unsigned short*)A + (size_t)i * NNODES + lane * 64);
        #pragma unroll
        for (int q = 0; q < 8; ++q) {          // 8 x uint4 = 64 bf16
            uint4 p = ap[q];
            unsigned int w[4] = {p.x, p.y, p.z, p.w};
            #pragma unroll
            for (int r = 0; r < 4; ++r) {
                int b = q * 8 + r * 2;
                if (w[r] & 0x0000ffffu) bits |= 1ull << b;
                if (w[r] & 0xffff0000u) bits |= 1ull << (b + 1);
            }
        }
    }

    // ---- wave-uniform edge stream state ----
    u64 nz = __ballot(bits != 0);   // lanes with >=1 edge (uniform)
    u64 cur = 0;
    int curbase = 0;

    auto next_edge = [&]() -> int {
        while (cur == 0) {
            if (nz == 0) return -1;
            int sl = __ffsll(nz) - 1;
            nz &= nz - 1;
            cur = __shfl(bits, sl, 64);         // uniform 64-bit chunk
            curbase = sl << 6;
        }
        int b = __ffsll(cur) - 1;
        cur &= cur - 1;
        return curbase + b;
    };

    const int c = lane, h = lane >> 3;
    const float ash = a_self_g[i * NH + h];
    float acc = 0.f, den = 0.f;

    for (;;) {
        int j0 = next_edge();
        if (j0 < 0) break;
        int j1 = next_edge(); bool v1 = (j1 >= 0); j1 = v1 ? j1 : 0;
        int j2 = next_edge(); bool v2 = (j2 >= 0); j2 = v2 ? j2 : 0;
        int j3 = next_edge(); bool v3 = (j3 >= 0); j3 = v3 ? j3 : 0;

        // issue all 8 loads before consuming (ILP)
        float an0 = a_neigh[j0 * NH + h];
        float an1 = a_neigh[j1 * NH + h];
        float an2 = a_neigh[j2 * NH + h];
        float an3 = a_neigh[j3 * NH + h];
        float f0 = feats[j0 * HD + c];
        float f1 = feats[j1 * HD + c];
        float f2 = feats[j2 * HD + c];
        float f3 = feats[j3 * HD + c];

        if (!v1) an1 = -1e30f;   // exp -> 0: dead slot contributes nothing
        if (!v2) an2 = -1e30f;
        if (!v3) an3 = -1e30f;

        float s0 = ash + an0; s0 = (s0 >= 0.f) ? s0 : 0.2f * s0; float w0 = __expf(s0);
        float s1 = ash + an1; s1 = (s1 >= 0.f) ? s1 : 0.2f * s1; float w1 = __expf(s1);
        float s2 = ash + an2; s2 = (s2 >= 0.f) ? s2 : 0.2f * s2; float w2 = __expf(s2);
        float s3 = ash + an3; s3 = (s3 >= 0.f) ? s3 : 0.2f * s3; float w3 = __expf(s3);

        acc = fmaf(w0, f0, acc);
        acc = fmaf(w1, f1, acc);
        acc = fmaf(w2, f2, acc);
        acc = fmaf(w3, f3, acc);
        den += (w0 + w1) + (w2 + w3);
    }

    // self loop guarantees den > 0; lanes in an h-group hold identical den.
    float v = acc / den + ldv(bias, c, f32);
    out[(size_t)i * HD + c] = fmaxf(v, 0.f);   // f32 output
}

// ---------------------------------------------------------------------------
extern "C" void kernel_launch(void* const* d_in, const int* in_sizes, int n_in,
                              void* d_out, int out_size, void* d_ws, size_t ws_size,
                              hipStream_t stream) {
    const void* X         = d_in[0];
    const void* A         = d_in[1];
    const void* W         = d_in[2];
    const void* att_self  = d_in[3];
    const void* att_neigh = d_in[4];
    const void* bias      = d_in[5];
    float* out = (float*)d_out;

    float* feats   = (float*)d_ws;                  // 4096*64 f32 = 1 MB
    float* a_self  = feats  + NNODES * HD;          // 4096*8  f32
    float* a_neigh = a_self + NNODES * NH;          // 4096*8  f32

    gat_feats<<<NNODES / 4, 256, 0, stream>>>(X, W, att_self, att_neigh, A,
                                              feats, a_self, a_neigh);
    gat_aggr<<<NNODES / 4, 256, 0, stream>>>(A, feats, a_self, a_neigh, bias, out);
}

// Round 7
// 28.548 us; speedup vs baseline: 1.7259x; 1.7259x over previous
//
#include <hip/hip_runtime.h>
#include <hip/hip_bf16.h>

#define NNODES 4096
#define NF 64
#define NH 8
#define ND 8
#define HD 64   // NH*ND

// Load element i from a buffer that is either f32 or bf16 (uniform flag).
__device__ __forceinline__ float ldv(const void* p, int i, bool f32) {
    return f32 ? ((const float*)p)[i]
               : __bfloat162float(((const __hip_bfloat16*)p)[i]);
}

// A[0][0] == 1.0 always (self loop): first u32 == 0x3F800000 iff A is f32.
__device__ __forceinline__ bool a_is_f32(const void* A) {
    return *(const unsigned int*)A == 0x3F800000u;
}

// ---------------------------------------------------------------------------
// Kernel 1: feats = X @ W (f32), plus a_self/a_neigh logits per node.
// Block = 256 threads handles 4 rows of X. W staged in LDS as f32.
// (proven in round 4, unchanged)
// ---------------------------------------------------------------------------
__global__ __launch_bounds__(256) void gat_feats(
    const void* __restrict__ X,
    const void* __restrict__ W,
    const void* __restrict__ att_self,
    const void* __restrict__ att_neigh,
    const void* __restrict__ A,
    float* __restrict__ feats,
    float* __restrict__ a_self,
    float* __restrict__ a_neigh)
{
    const bool f32 = a_is_f32(A);
    __shared__ float Wl[NF][HD];   // 16 KB
    __shared__ float Xl[4][NF];

    const int t = threadIdx.x;

    #pragma unroll
    for (int k = 0; k < 16; ++k) {
        int idx = t + k * 256;
        Wl[idx >> 6][idx & 63] = ldv(W, idx, f32);
    }

    const int n0 = blockIdx.x * 4;
    const int r = t >> 6;       // row within block (== wave id)
    const int c = t & 63;       // output column = h*8+d (== lane)
    Xl[r][c] = ldv(X, (n0 + r) * NF + c, f32);
    __syncthreads();

    float acc = 0.f;
    #pragma unroll
    for (int k = 0; k < NF; ++k)
        acc = fmaf(Xl[r][k], Wl[k][c], acc);

    const int n = n0 + r;
    feats[n * HD + c] = acc;

    const int d = c & 7;
    const int h = c >> 3;
    float vs = acc * ldv(att_self, c, f32);
    float vn = acc * ldv(att_neigh, c, f32);
    #pragma unroll
    for (int off = 1; off < 8; off <<= 1) {
        vs += __shfl_xor(vs, off, 64);
        vn += __shfl_xor(vn, off, 64);
    }
    if (d == 0) {
        a_self[n * NH + h]  = vs;
        a_neigh[n * NH + h] = vn;
    }
}

// ---------------------------------------------------------------------------
// Kernel 2: per-row masked softmax + aggregation. One block (256 thr) per row.
// Round-4 structure; phase 2 widened to 8-deep batches (16 gathers in flight).
// ---------------------------------------------------------------------------
__global__ __launch_bounds__(256) void gat_aggr(
    const void* __restrict__ A,
    const float* __restrict__ feats,
    const float* __restrict__ a_self_g,
    const float* __restrict__ a_neigh,
    const void* __restrict__ bias,
    float* __restrict__ out)
{
    const int i = blockIdx.x;
    const int t = threadIdx.x;
    const bool f32 = a_is_f32(A);
    const int wave = t >> 6, lane = t & 63;

    __shared__ unsigned short elist[NNODES];  // 8 KB worst-case edge list
    __shared__ int wtot[4];
    __shared__ float red[4][HD];
    __shared__ float dsh[4][NH];

    // ---- Phase 0: read this thread's 16 consecutive A entries -> bits ----
    unsigned int bits = 0;
    if (f32) {
        const uint4* ap = (const uint4*)((const float*)A + (size_t)i * NNODES + t * 16);
        #pragma unroll
        for (int q = 0; q < 4; ++q) {
            uint4 p = ap[q];
            if (p.x) bits |= 1u << (4 * q + 0);
            if (p.y) bits |= 1u << (4 * q + 1);
            if (p.z) bits |= 1u << (4 * q + 2);
            if (p.w) bits |= 1u << (4 * q + 3);
        }
    } else {
        const uint4* ap = (const uint4*)((const unsigned short*)A + (size_t)i * NNODES + t * 16);
        uint4 p0 = ap[0], p1 = ap[1];
        unsigned int w0[4] = {p0.x, p0.y, p0.z, p0.w};
        unsigned int w1[4] = {p1.x, p1.y, p1.z, p1.w};
        #pragma unroll
        for (int q = 0; q < 4; ++q) {
            if (w0[q] & 0x0000ffffu) bits |= 1u << (2 * q);
            if (w0[q] & 0xffff0000u) bits |= 1u << (2 * q + 1);
            if (w1[q] & 0x0000ffffu) bits |= 1u << (8 + 2 * q);
            if (w1[q] & 0xffff0000u) bits |= 1u << (8 + 2 * q + 1);
        }
    }

    // ---- Phase 1: deterministic compaction into elist (ascending j) ----
    int cnt = __popc(bits);
    int incl = cnt;
    #pragma unroll
    for (int off = 1; off < 64; off <<= 1) {
        int nn = __shfl_up(incl, off, 64);
        if (lane >= off) incl += nn;
    }
    if (lane == 63) wtot[wave] = incl;
    __syncthreads();
    int base = 0;
    #pragma unroll
    for (int w = 0; w < 4; ++w) if (w < wave) base += wtot[w];
    const int nE = wtot[0] + wtot[1] + wtot[2] + wtot[3];
    int off0 = base + (incl - cnt);
    unsigned int mb = bits;
    while (mb) {
        int b = __ffs(mb) - 1; mb &= mb - 1;
        elist[off0++] = (unsigned short)(t * 16 + b);
    }
    __syncthreads();

    // ---- Phase 2: aggregate; wave takes a contiguous chunk, 8-deep batches --
    const int c = lane;
    const int h = c >> 3, d = c & 7;
    const float ash = a_self_g[i * NH + h];
    float acc = 0.f, den = 0.f;

    const int chunk = (nE + 3) >> 2;
    int e = wave * chunk;
    const int eEnd = min(nE, e + chunk);

    for (; e + 8 <= eEnd; e += 8) {
        int j[8];
        #pragma unroll
        for (int k = 0; k < 8; ++k) j[k] = elist[e + k];
        float an[8], fv[8];
        #pragma unroll
        for (int k = 0; k < 8; ++k) an[k] = a_neigh[j[k] * NH + h];
        #pragma unroll
        for (int k = 0; k < 8; ++k) fv[k] = feats[j[k] * HD + c];
        #pragma unroll
        for (int k = 0; k < 8; ++k) {
            float s = ash + an[k];
            s = (s >= 0.f) ? s : 0.2f * s;
            float wt = __expf(s);
            acc = fmaf(wt, fv[k], acc);
            den += wt;
        }
    }
    for (; e + 4 <= eEnd; e += 4) {
        int j[4];
        #pragma unroll
        for (int k = 0; k < 4; ++k) j[k] = elist[e + k];
        float an[4], fv[4];
        #pragma unroll
        for (int k = 0; k < 4; ++k) an[k] = a_neigh[j[k] * NH + h];
        #pragma unroll
        for (int k = 0; k < 4; ++k) fv[k] = feats[j[k] * HD + c];
        #pragma unroll
        for (int k = 0; k < 4; ++k) {
            float s = ash + an[k];
            s = (s >= 0.f) ? s : 0.2f * s;
            float wt = __expf(s);
            acc = fmaf(wt, fv[k], acc);
            den += wt;
        }
    }
    for (; e < eEnd; ++e) {
        int j = elist[e];
        float s = ash + a_neigh[j * NH + h];
        s = (s >= 0.f) ? s : 0.2f * s;
        float wt = __expf(s);
        acc = fmaf(wt, feats[j * HD + c], acc);
        den += wt;
    }

    red[wave][c] = acc;
    if (d == 0) dsh[wave][h] = den;
    __syncthreads();

    if (t < HD) {
        float tot = red[0][t] + red[1][t] + red[2][t] + red[3][t];
        int hh = t >> 3;
        float dd = dsh[0][hh] + dsh[1][hh] + dsh[2][hh] + dsh[3][hh];
        float v = tot / dd + ldv(bias, t, f32);
        out[(size_t)i * HD + t] = fmaxf(v, 0.f);   // f32 output
    }
}

// ---------------------------------------------------------------------------
extern "C" void kernel_launch(void* const* d_in, const int* in_sizes, int n_in,
                              void* d_out, int out_size, void* d_ws, size_t ws_size,
                              hipStream_t stream) {
    const void* X         = d_in[0];
    const void* A         = d_in[1];
    const void* W         = d_in[2];
    const void* att_self  = d_in[3];
    const void* att_neigh = d_in[4];
    const void* bias      = d_in[5];
    float* out = (float*)d_out;

    float* feats   = (float*)d_ws;                  // 4096*64 f32 = 1 MB
    float* a_self  = feats  + NNODES * HD;          // 4096*8  f32
    float* a_neigh = a_self + NNODES * NH;          // 4096*8  f32

    gat_feats<<<NNODES / 4, 256, 0, stream>>>(X, W, att_self, att_neigh, A,
                                              feats, a_self, a_neigh);
    gat_aggr<<<NNODES, 256, 0, stream>>>(A, feats, a_self, a_neigh, bias, out);
}